// Round 8
// baseline (475.573 us; speedup 1.0000x reference)
//
#include <hip/hip_runtime.h>
#include <math.h>

#define BB 32     // batch
#define TT 64     // time steps
#define VV 32000  // vocab
#define HH 32     // hidden
#define EE 200    // embedding dim
#define MM (BB * TT)      // 2048 GEMM rows (r = b*TT + t)
#define VC 16             // stats v-chunks (2000 cols each)
#define VTPC 125          // 16-col v-tiles per chunk
#define NWE (VV * HH)     // Wo element count
#define WLB ((NWE + 255) / 256)   // 4000 W-limb blocks in k_pre
#define ZB 8              // zero-init blocks for gsum/gkey (8*256 = 2048)

typedef __attribute__((ext_vector_type(8))) short short8;   // 8 bf16 = 4 VGPR
typedef __attribute__((ext_vector_type(4))) float f32x4;

// x = l0 + l1 + l2 with li bf16 (RNE): combined ~26 mantissa bits >= f32's 24.
__device__ inline void split3(float x, ushort& u0, ushort& u1, ushort& u2) {
    unsigned a = __float_as_uint(x);
    ushort t0 = (ushort)((a + 0x7FFFu + ((a >> 16) & 1u)) >> 16);
    float f0 = __uint_as_float(((unsigned)t0) << 16);
    float r1 = x - f0;
    unsigned b = __float_as_uint(r1);
    ushort t1 = (ushort)((b + 0x7FFFu + ((b >> 16) & 1u)) >> 16);
    float f1 = __uint_as_float(((unsigned)t1) << 16);
    float r2 = r1 - f1;
    unsigned c = __float_as_uint(r2);
    ushort t2 = (ushort)((c + 0x7FFFu + ((c >> 16) & 1u)) >> 16);
    u0 = t0; u1 = t1; u2 = t2;
}

// 6-product bf16x3 MFMA: a*b to ~1e-7 relative. Small terms first.
__device__ inline f32x4 mfma6(short8 a0, short8 a1, short8 a2,
                              short8 b0, short8 b1, short8 b2) {
    f32x4 acc = {0.f, 0.f, 0.f, 0.f};
    acc = __builtin_amdgcn_mfma_f32_16x16x32_bf16(a2, b0, acc, 0, 0, 0);
    acc = __builtin_amdgcn_mfma_f32_16x16x32_bf16(a0, b2, acc, 0, 0, 0);
    acc = __builtin_amdgcn_mfma_f32_16x16x32_bf16(a1, b1, acc, 0, 0, 0);
    acc = __builtin_amdgcn_mfma_f32_16x16x32_bf16(a1, b0, acc, 0, 0, 0);
    acc = __builtin_amdgcn_mfma_f32_16x16x32_bf16(a0, b1, acc, 0, 0, 0);
    acc = __builtin_amdgcn_mfma_f32_16x16x32_bf16(a0, b0, acc, 0, 0, 0);
    return acc;
}

// order-preserving u32 encoding of a (non-NaN) float; pack with ~v for argmax:
// larger logit wins; equal logits -> larger (0xFFFFFFFF - v) -> smaller v first.
__device__ inline unsigned long long packkey(float g, unsigned v) {
    unsigned bits = __float_as_uint(g);
    unsigned e = (bits & 0x80000000u) ? ~bits : (bits | 0x80000000u);
    return ((unsigned long long)e << 32) | (unsigned long long)(0xFFFFFFFFu - v);
}

// ---------------- Kernel 1 (fused): i2h GEMV + W-limb split + stat zero --------
// Blocks [0,MM): i2h = emb[y] @ Wi.T + bi + bh.
// Blocks [MM, MM+WLB): split 256 Wo elements each into bf16 limbs.
// Blocks [MM+WLB, MM+WLB+ZB): zero gsum/gkey accumulators (2048 each).
__global__ __launch_bounds__(256) void k_pre(
        const int* __restrict__ y, const float* __restrict__ emb,
        const float* __restrict__ Wi, const float* __restrict__ bi,
        const float* __restrict__ bh, const float* __restrict__ Wo,
        float* __restrict__ i2h,
        ushort* __restrict__ W0, ushort* __restrict__ W1, ushort* __restrict__ W2,
        float* __restrict__ gsum, unsigned long long* __restrict__ gkey) {
    int blk = blockIdx.x;
    if (blk >= MM + WLB) {            // ---- zero stats accumulators ----
        int i = (blk - MM - WLB) * 256 + (int)threadIdx.x;
        if (i < MM) { gsum[i] = 0.f; gkey[i] = 0ull; }
        return;
    }
    if (blk >= MM) {                  // ---- W-limb split ----
        int i = (blk - MM) * 256 + (int)threadIdx.x;
        if (i < NWE) {
            ushort u0, u1, u2; split3(Wo[i], u0, u1, u2);
            W0[i] = u0; W1[i] = u1; W2[i] = u2;
        }
        return;
    }
    int tok = y[blk];
    __shared__ float se[EE];
    for (int e = threadIdx.x; e < EE; e += 256) se[e] = emb[(size_t)tok * EE + e];
    __syncthreads();
    int h = threadIdx.x >> 3;         // 0..31
    int j = threadIdx.x & 7;          // 8 lanes per h
    float acc = 0.f;
    for (int e = j; e < EE; e += 8) acc += se[e] * Wi[h * EE + e];
    acc += __shfl_down(acc, 4, 8);
    acc += __shfl_down(acc, 2, 8);
    acc += __shfl_down(acc, 1, 8);
    if (j == 0) i2h[blk * HH + h] = acc + bi[h] + bh[h];
}

// ---------------- Kernel 2: recurrence, writes H LIMBS directly ----------------
__global__ void k_rnn(const float* __restrict__ enc, const float* __restrict__ Wh,
                      const float* __restrict__ i2h,
                      ushort* __restrict__ H0, ushort* __restrict__ H1,
                      ushort* __restrict__ H2) {
    int b = blockIdx.x;               // 0..31
    int tid = threadIdx.x;            // 64 threads = 1 wave
    __shared__ float hs[HH];
    __shared__ float sWh[HH][HH + 1];
    __shared__ float si[TT * HH];
    for (int i = tid; i < HH * HH; i += 64) sWh[i >> 5][i & 31] = Wh[i];
    for (int i = tid; i < TT * HH; i += 64) si[i] = i2h[b * TT * HH + i];
    if (tid < HH) hs[tid] = enc[b * HH + tid];
    __syncthreads();
    for (int t = 0; t < TT; ++t) {
        float hv = 0.f;
        if (tid < HH) {
            float a0 = si[t * HH + tid], a1 = 0.f, a2 = 0.f, a3 = 0.f;
#pragma unroll
            for (int j = 0; j < HH; j += 4) {
                a0 += sWh[tid][j]     * hs[j];
                a1 += sWh[tid][j + 1] * hs[j + 1];
                a2 += sWh[tid][j + 2] * hs[j + 2];
                a3 += sWh[tid][j + 3] * hs[j + 3];
            }
            hv = tanhf((a0 + a1) + (a2 + a3));
        }
        __syncthreads();
        if (tid < HH) {
            hs[tid] = hv;
            ushort u0, u1, u2; split3(hv, u0, u1, u2);
            int idx = (b * TT + t) * HH + tid;
            H0[idx] = u0; H1[idx] = u1; H2[idx] = u2;
        }
        __syncthreads();
    }
}

// ---------------- Kernel 3: stats via MFMA -> device-atomic merge --------------
// 1-D grid of 128 blocks, XCD-colocating swizzle: id = xcd + 8*(y + 8*chi),
// c = chi*8 + xcd. The 8 blocks sharing chunk c land on ONE XCD (consecutive
// blockIdx round-robin across 8 XCDs) -> the chunk's 1.15 MB of W limbs goes
// L2-resident (per-XCD traffic ~2 chunks = 2.3 MB < 4 MB L2).
// Wave owns 4 M-tiles (A-frags 48 VGPRs); every B-limb load feeds 4 mfma6.
// Epilogue: atomicAdd exp-sum (order noise ~1e-6 << tol) + 64-bit atomicMax
// argmax key (deterministic: max + smaller-v tiebreak are order-independent).
__global__ __launch_bounds__(256) void k_stats_mfma(
        const ushort* __restrict__ W0, const ushort* __restrict__ W1, const ushort* __restrict__ W2,
        const ushort* __restrict__ H0, const ushort* __restrict__ H1, const ushort* __restrict__ H2,
        const float* __restrict__ bo,
        float* __restrict__ gsum, unsigned long long* __restrict__ gkey) {
    int id   = blockIdx.x;            // 0..127
    int xcd  = id & 7;
    int yrow = (id >> 3) & 7;         // 0..7
    int chi  = id >> 6;               // 0..1
    int c    = chi * 8 + xcd;         // 0..15
    int wv = threadIdx.x >> 6;
    int l  = threadIdx.x & 63;
    int lc = l & 15, lg = l >> 4;
    int Tb = (yrow * 4 + wv) * 4;     // first of this wave's 4 M-tiles (0..124)

    short8 a0[4], a1[4], a2[4];
#pragma unroll
    for (int i = 0; i < 4; ++i) {
        size_t aoff = (size_t)((Tb + i) * 16 + lc) * HH + lg * 8;
        a0[i] = *(const short8*)(H0 + aoff);
        a1[i] = *(const short8*)(H1 + aoff);
        a2[i] = *(const short8*)(H2 + aoff);
    }

    float mx[4][4], am[4][4], sm[4][4];
#pragma unroll
    for (int i = 0; i < 4; ++i)
#pragma unroll
        for (int q = 0; q < 4; ++q) { mx[i][q] = -1e30f; am[i][q] = 0.f; sm[i][q] = 0.f; }

    int vb = c * (VTPC * 16);         // chunk base column
#pragma unroll 2
    for (int s = 0; s < VTPC; ++s) {
        int v = vb + s * 16 + lc;
        size_t boff = (size_t)v * HH + lg * 8;
        short8 b0 = *(const short8*)(W0 + boff);
        short8 b1 = *(const short8*)(W1 + boff);
        short8 b2 = *(const short8*)(W2 + boff);
        float bov = bo[v];
        float vf  = (float)v;
#pragma unroll
        for (int i = 0; i < 4; ++i) {
            f32x4 acc = mfma6(a0[i], a1[i], a2[i], b0, b1, b2);
#pragma unroll
            for (int q = 0; q < 4; ++q) {
                float g = acc[q] + bov;
                sm[i][q] += __expf(g);    // |logit| < ~6: exp w/o max-shift safe
                if (g > mx[i][q]) { mx[i][q] = g; am[i][q] = vf; }  // strict >: first occ.
            }
        }
    }

    // reduce across the 16 lanes (lc bits) sharing the same rows
#pragma unroll
    for (int i = 0; i < 4; ++i)
#pragma unroll
        for (int q = 0; q < 4; ++q) {
#pragma unroll
            for (int msk = 1; msk <= 8; msk <<= 1) {
                float m2 = __shfl_xor(mx[i][q], msk);
                float av = __shfl_xor(am[i][q], msk);
                float s2 = __shfl_xor(sm[i][q], msk);
                sm[i][q] += s2;
                if (m2 > mx[i][q] || (m2 == mx[i][q] && av < am[i][q])) {
                    mx[i][q] = m2; am[i][q] = av;
                }
            }
        }
    if (lc == 0) {                    // lanes 0,16,32,48: publish 16 rows each
#pragma unroll
        for (int i = 0; i < 4; ++i) {
            int base = (Tb + i) * 16 + lg * 4;
#pragma unroll
            for (int q = 0; q < 4; ++q) {
                atomicAdd(&gsum[base + q], sm[i][q]);
                atomicMax(&gkey[base + q], packkey(mx[i][q], (unsigned)am[i][q]));
            }
        }
    }
}

// ---------------- Kernel 4: logits via MFMA, on-the-fly W conversion -----------
// grid (1000, 4), 1 wave. Block owns 32 vocab cols: converts those 32 Wo rows to
// limb frags ONCE in registers, then loops 32 M-tiles. Same split3+mfma6 as
// stats => identical logits. lse computed as logf(gsum) in the prologue;
// blockIdx.x==0 blocks also emit preds from gkey. Nontemporal stores keep the
// 262 MB output stream from evicting the limb working set out of L2.
__global__ __launch_bounds__(64) void k_write_conv(
        const float* __restrict__ Wo,
        const ushort* __restrict__ H0, const ushort* __restrict__ H1, const ushort* __restrict__ H2,
        const float* __restrict__ bo,
        const float* __restrict__ gsum, const unsigned long long* __restrict__ gkey,
        float* __restrict__ out, float* __restrict__ preds) {
    int v0 = blockIdx.x * 32;
    int lc = threadIdx.x & 15, lg = threadIdx.x >> 4;
    int mbase = blockIdx.y * (MM / 4);          // 512 rows per block

    __shared__ float sl[MM / 4];
    for (int i = threadIdx.x; i < MM / 4; i += 64) sl[i] = logf(gsum[mbase + i]);
    if (blockIdx.x == 0) {                      // 4 blocks emit preds (512 each)
        for (int i = threadIdx.x; i < MM / 4; i += 64) {
            unsigned low = (unsigned)(gkey[mbase + i] & 0xFFFFFFFFull);
            preds[mbase + i] = (float)(0xFFFFFFFFu - low);
        }
    }

    short8 b0a, b1a, b2a, b0b, b1b, b2b;
    {
        const float* ra = Wo + (size_t)(v0 + lc) * HH + lg * 8;
        const float* rb = ra + 16 * HH;
#pragma unroll
        for (int j = 0; j < 8; ++j) {
            ushort u0, u1, u2; split3(ra[j], u0, u1, u2);
            b0a[j] = (short)u0; b1a[j] = (short)u1; b2a[j] = (short)u2;
        }
#pragma unroll
        for (int j = 0; j < 8; ++j) {
            ushort u0, u1, u2; split3(rb[j], u0, u1, u2);
            b0b[j] = (short)u0; b1b[j] = (short)u1; b2b[j] = (short)u2;
        }
    }
    float boA = bo[v0 + lc], boB = bo[v0 + 16 + lc];
    __syncthreads();

    for (int s = 0; s < MM / 4 / 16; ++s) {     // 32 M-tiles
        int m0 = mbase + s * 16;
        size_t aoff = (size_t)(m0 + lc) * HH + lg * 8;
        short8 a0 = *(const short8*)(H0 + aoff);
        short8 a1 = *(const short8*)(H1 + aoff);
        short8 a2 = *(const short8*)(H2 + aoff);
        f32x4 accA = mfma6(a0, a1, a2, b0a, b1a, b2a);
        f32x4 accB = mfma6(a0, a1, a2, b0b, b1b, b2b);
        int row = m0 + lg * 4;
        int lrow = s * 16 + lg * 4;
#pragma unroll
        for (int q = 0; q < 4; ++q) {
            float ls = sl[lrow + q];
            size_t ob = (size_t)(row + q) * VV + v0 + lc;
            __builtin_nontemporal_store(accA[q] + boA - ls, &out[ob]);
            __builtin_nontemporal_store(accB[q] + boB - ls, &out[ob + 16]);
        }
    }
}

// ---------------- Launch -------------------------------------------------------
extern "C" void kernel_launch(void* const* d_in, const int* in_sizes, int n_in,
                              void* d_out, int out_size, void* d_ws, size_t ws_size,
                              hipStream_t stream) {
    const int*   y   = (const int*)  d_in[0];
    const float* enc = (const float*)d_in[1];
    const float* emb = (const float*)d_in[2];
    const float* Wi  = (const float*)d_in[3];
    const float* bi  = (const float*)d_in[4];
    const float* Wh  = (const float*)d_in[5];
    const float* bh  = (const float*)d_in[6];
    const float* Wo  = (const float*)d_in[7];
    const float* bo  = (const float*)d_in[8];
    float* out = (float*)d_out;
    float* ws  = (float*)d_ws;

    // workspace (floats) — 169,984 floats = 680 KB (<= 1.32 MB proven-safe cap).
    float* i2h  = ws;                        // [0, 65536)
    ushort* H0  = (ushort*)(ws + 65536);     // [65536, 163840): 3 x 65,536 ushorts
    ushort* H1  = H0 + MM * HH;
    ushort* H2  = H1 + MM * HH;
    float* gsum = ws + 163840;               // [163840, 165888): 2048 f32
    unsigned long long* gkey =
        (unsigned long long*)(ws + 165888);  // [165888, 169984): 2048 u64 (8B-aligned)

    // W limbs: scratch inside the (not-yet-written) logprobs output region.
    ushort* W0 = (ushort*)out;               // 3 x 1,024,000 ushorts = 6.1 MB
    ushort* W1 = W0 + NWE;
    ushort* W2 = W1 + NWE;
    float* preds = out + (size_t)MM * VV;

    k_pre<<<MM + WLB + ZB, 256, 0, stream>>>(y, emb, Wi, bi, bh, Wo, i2h,
                                             W0, W1, W2, gsum, gkey);
    k_rnn<<<BB, 64, 0, stream>>>(enc, Wh, i2h, H0, H1, H2);
    k_stats_mfma<<<128, 256, 0, stream>>>(W0, W1, W2, H0, H1, H2, bo, gsum, gkey);
    dim3 gw(1000, 4);
    k_write_conv<<<gw, 64, 0, stream>>>(Wo, H0, H1, H2, bo, gsum, gkey, out, preds);
}

// Round 9
// 430.020 us; speedup vs baseline: 1.1059x; 1.1059x over previous
//
#include <hip/hip_runtime.h>
#include <math.h>

#define BB 32     // batch
#define TT 64     // time steps
#define VV 32000  // vocab
#define HH 32     // hidden
#define EE 200    // embedding dim
#define MM (BB * TT)      // 2048 GEMM rows (r = b*TT + t)
#define VC 25             // stats v-chunks
#define VTPC 80           // 16-col v-tiles per chunk (1280 cols)
#define NWE (VV * HH)     // Wo element count
#define WLB ((NWE + 255) / 256)   // 4000 W-limb blocks in k_pre

typedef __attribute__((ext_vector_type(8))) short short8;   // 8 bf16 = 4 VGPR
typedef __attribute__((ext_vector_type(4))) float f32x4;

// x = l0 + l1 + l2 with li bf16 (RNE): combined ~26 mantissa bits >= f32's 24.
__device__ inline void split3(float x, ushort& u0, ushort& u1, ushort& u2) {
    unsigned a = __float_as_uint(x);
    ushort t0 = (ushort)((a + 0x7FFFu + ((a >> 16) & 1u)) >> 16);
    float f0 = __uint_as_float(((unsigned)t0) << 16);
    float r1 = x - f0;
    unsigned b = __float_as_uint(r1);
    ushort t1 = (ushort)((b + 0x7FFFu + ((b >> 16) & 1u)) >> 16);
    float f1 = __uint_as_float(((unsigned)t1) << 16);
    float r2 = r1 - f1;
    unsigned c = __float_as_uint(r2);
    ushort t2 = (ushort)((c + 0x7FFFu + ((c >> 16) & 1u)) >> 16);
    u0 = t0; u1 = t1; u2 = t2;
}

// 6-product bf16x3 MFMA: a*b to ~1e-7 relative. Small terms first.
__device__ inline f32x4 mfma6(short8 a0, short8 a1, short8 a2,
                              short8 b0, short8 b1, short8 b2) {
    f32x4 acc = {0.f, 0.f, 0.f, 0.f};
    acc = __builtin_amdgcn_mfma_f32_16x16x32_bf16(a2, b0, acc, 0, 0, 0);
    acc = __builtin_amdgcn_mfma_f32_16x16x32_bf16(a0, b2, acc, 0, 0, 0);
    acc = __builtin_amdgcn_mfma_f32_16x16x32_bf16(a1, b1, acc, 0, 0, 0);
    acc = __builtin_amdgcn_mfma_f32_16x16x32_bf16(a1, b0, acc, 0, 0, 0);
    acc = __builtin_amdgcn_mfma_f32_16x16x32_bf16(a0, b1, acc, 0, 0, 0);
    acc = __builtin_amdgcn_mfma_f32_16x16x32_bf16(a0, b0, acc, 0, 0, 0);
    return acc;
}

// ---------------- Kernel 1 (fused): i2h GEMV + W-limb split --------------------
// Blocks 0..MM-1: i2h = emb[y] @ Wi.T + bi + bh. Blocks MM..MM+WLB-1: split 256
// Wo elements each into bf16 limbs (stored in the out-region scratch).
__global__ __launch_bounds__(256) void k_pre(
        const int* __restrict__ y, const float* __restrict__ emb,
        const float* __restrict__ Wi, const float* __restrict__ bi,
        const float* __restrict__ bh, const float* __restrict__ Wo,
        float* __restrict__ i2h,
        ushort* __restrict__ W0, ushort* __restrict__ W1, ushort* __restrict__ W2) {
    int blk = blockIdx.x;
    if (blk >= MM) {
        int i = (blk - MM) * 256 + (int)threadIdx.x;
        if (i < NWE) {
            ushort u0, u1, u2; split3(Wo[i], u0, u1, u2);
            W0[i] = u0; W1[i] = u1; W2[i] = u2;
        }
        return;
    }
    int tok = y[blk];
    __shared__ float se[EE];
    for (int e = threadIdx.x; e < EE; e += 256) se[e] = emb[(size_t)tok * EE + e];
    __syncthreads();
    int h = threadIdx.x >> 3;         // 0..31
    int j = threadIdx.x & 7;          // 8 lanes per h
    float acc = 0.f;
    for (int e = j; e < EE; e += 8) acc += se[e] * Wi[h * EE + e];
    acc += __shfl_down(acc, 4, 8);
    acc += __shfl_down(acc, 2, 8);
    acc += __shfl_down(acc, 1, 8);
    if (j == 0) i2h[blk * HH + h] = acc + bi[h] + bh[h];
}

// ---------------- Kernel 2: recurrence, writes H LIMBS directly ----------------
// h_t = tanh(i2h_t + h_{t-1} @ Wh.T); epilogue splits hv into bf16 limbs in
// registers -> no f32 hall array, no separate H-limb pass.
__global__ void k_rnn(const float* __restrict__ enc, const float* __restrict__ Wh,
                      const float* __restrict__ i2h,
                      ushort* __restrict__ H0, ushort* __restrict__ H1,
                      ushort* __restrict__ H2) {
    int b = blockIdx.x;               // 0..31
    int tid = threadIdx.x;            // 64 threads = 1 wave
    __shared__ float hs[HH];
    __shared__ float sWh[HH][HH + 1];
    __shared__ float si[TT * HH];
    for (int i = tid; i < HH * HH; i += 64) sWh[i >> 5][i & 31] = Wh[i];
    for (int i = tid; i < TT * HH; i += 64) si[i] = i2h[b * TT * HH + i];
    if (tid < HH) hs[tid] = enc[b * HH + tid];
    __syncthreads();
    for (int t = 0; t < TT; ++t) {
        float hv = 0.f;
        if (tid < HH) {
            float a0 = si[t * HH + tid], a1 = 0.f, a2 = 0.f, a3 = 0.f;
#pragma unroll
            for (int j = 0; j < HH; j += 4) {
                a0 += sWh[tid][j]     * hs[j];
                a1 += sWh[tid][j + 1] * hs[j + 1];
                a2 += sWh[tid][j + 2] * hs[j + 2];
                a3 += sWh[tid][j + 3] * hs[j + 3];
            }
            hv = tanhf((a0 + a1) + (a2 + a3));
        }
        __syncthreads();
        if (tid < HH) {
            hs[tid] = hv;
            ushort u0, u1, u2; split3(hv, u0, u1, u2);
            int idx = (b * TT + t) * HH + tid;
            H0[idx] = u0; H1[idx] = u1; H2[idx] = u2;
        }
        __syncthreads();
    }
}

// ---------------- Kernel 3: stats via MFMA -------------------------------------
// grid (VC=25, 32), 256 thr = 4 independent waves (no barriers); wave w owns
// M-tile blockIdx.y*4+w. All 4 waves stream the same W-limb tiles -> L1 dedup.
// C/D layout [m89]: col=lane&15 (v), row=(lane>>4)*4+q (m). Stats in 12 VGPRs.
__global__ __launch_bounds__(256) void k_stats_mfma(
        const ushort* __restrict__ W0, const ushort* __restrict__ W1, const ushort* __restrict__ W2,
        const ushort* __restrict__ H0, const ushort* __restrict__ H1, const ushort* __restrict__ H2,
        const float* __restrict__ bo,
        float* __restrict__ pmax, float* __restrict__ pamx, float* __restrict__ psum) {
    int c  = blockIdx.x;
    int wv = threadIdx.x >> 6;
    int l  = threadIdx.x & 63;
    int lc = l & 15, lg = l >> 4;
    int m0 = (blockIdx.y * 4 + wv) * 16;
    size_t aoff = (size_t)(m0 + lc) * HH + lg * 8;
    short8 a0 = *(const short8*)(H0 + aoff);
    short8 a1 = *(const short8*)(H1 + aoff);
    short8 a2 = *(const short8*)(H2 + aoff);

    float mx[4], am[4], sm[4];
#pragma unroll
    for (int q = 0; q < 4; ++q) { mx[q] = -1e30f; am[q] = 0.f; sm[q] = 0.f; }

    int vb = c * (VTPC * 16);         // chunk base column
#pragma unroll 5
    for (int s = 0; s < VTPC; ++s) {
        int v = vb + s * 16 + lc;     // this lane's vocab row in tile s
        size_t boff = (size_t)v * HH + lg * 8;
        short8 b0 = *(const short8*)(W0 + boff);
        short8 b1 = *(const short8*)(W1 + boff);
        short8 b2 = *(const short8*)(W2 + boff);
        f32x4 acc = mfma6(a0, a1, a2, b0, b1, b2);
        float bov = bo[v];
        float vf  = (float)v;
#pragma unroll
        for (int q = 0; q < 4; ++q) {
            float g = acc[q] + bov;
            sm[q] += __expf(g);       // |logit| < ~6: exp w/o max-shift is safe
            if (g > mx[q]) { mx[q] = g; am[q] = vf; }   // strict >: first-occurrence
        }
    }

    // reduce across the 16 lanes (lc bits) sharing the same 4 rows
#pragma unroll
    for (int q = 0; q < 4; ++q) {
#pragma unroll
        for (int msk = 1; msk <= 8; msk <<= 1) {
            float m2 = __shfl_xor(mx[q], msk);
            float av = __shfl_xor(am[q], msk);
            float s2 = __shfl_xor(sm[q], msk);
            sm[q] += s2;
            if (m2 > mx[q] || (m2 == mx[q] && av < am[q])) { mx[q] = m2; am[q] = av; }
        }
    }
    if (lc == 0) {
        int base = c * MM + m0 + lg * 4;
#pragma unroll
        for (int q = 0; q < 4; ++q) {
            pmax[base + q] = mx[q];
            pamx[base + q] = am[q];
            psum[base + q] = sm[q];
        }
    }
}

// ---------------- Kernel 4: combine partials -> lse, preds ---------------------
__global__ void k_combine(const float* __restrict__ pmax, const float* __restrict__ pamx,
                          const float* __restrict__ psum,
                          float* __restrict__ lse, float* __restrict__ preds) {
    int r = blockIdx.x * blockDim.x + threadIdx.x;   // r = b*TT + t
    if (r >= MM) return;
    float m = -1e30f, a = 0.f, s = 0.f;
    for (int c = 0; c < VC; ++c) {
        int idx = c * MM + r;
        float m2 = pmax[idx], a2 = pamx[idx];
        s += psum[idx];
        if (m2 > m || (m2 == m && a2 < a)) { m = m2; a = a2; }
    }
    lse[r] = logf(s);
    preds[r] = a;    // preds[b][t] (r = b*TT+t), index as float (exact to 2^24)
}

// ---------------- Kernel 5: logits via MFMA, on-the-fly W conversion -----------
// grid (1000, 4), 1 wave. Block owns 32 vocab cols: converts those 32 Wo rows to
// limb frags ONCE in registers (independent of the out-region limb scratch -> no
// race with overwriting it), then loops 32 M-tiles. Same split3+mfma6 as stats
// => bit-identical logits. lse slice in LDS. Roofline: the 262 MB output write.
__global__ __launch_bounds__(64) void k_write_conv(
        const float* __restrict__ Wo,
        const ushort* __restrict__ H0, const ushort* __restrict__ H1, const ushort* __restrict__ H2,
        const float* __restrict__ bo, const float* __restrict__ lse,
        float* __restrict__ out) {
    int v0 = blockIdx.x * 32;
    int lc = threadIdx.x & 15, lg = threadIdx.x >> 4;
    int mbase = blockIdx.y * (MM / 4);          // 512 rows per block

    __shared__ float sl[MM / 4];
    for (int i = threadIdx.x; i < MM / 4; i += 64) sl[i] = lse[mbase + i];

    short8 b0a, b1a, b2a, b0b, b1b, b2b;
    {
        const float* ra = Wo + (size_t)(v0 + lc) * HH + lg * 8;
        const float* rb = ra + 16 * HH;
#pragma unroll
        for (int j = 0; j < 8; ++j) {
            ushort u0, u1, u2; split3(ra[j], u0, u1, u2);
            b0a[j] = (short)u0; b1a[j] = (short)u1; b2a[j] = (short)u2;
        }
#pragma unroll
        for (int j = 0; j < 8; ++j) {
            ushort u0, u1, u2; split3(rb[j], u0, u1, u2);
            b0b[j] = (short)u0; b1b[j] = (short)u1; b2b[j] = (short)u2;
        }
    }
    float boA = bo[v0 + lc], boB = bo[v0 + 16 + lc];
    __syncthreads();

    for (int s = 0; s < MM / 4 / 16; ++s) {     // 32 M-tiles
        int m0 = mbase + s * 16;
        size_t aoff = (size_t)(m0 + lc) * HH + lg * 8;
        short8 a0 = *(const short8*)(H0 + aoff);
        short8 a1 = *(const short8*)(H1 + aoff);
        short8 a2 = *(const short8*)(H2 + aoff);
        f32x4 accA = mfma6(a0, a1, a2, b0a, b1a, b2a);
        f32x4 accB = mfma6(a0, a1, a2, b0b, b1b, b2b);
        int row = m0 + lg * 4;
        int lrow = s * 16 + lg * 4;
#pragma unroll
        for (int q = 0; q < 4; ++q) {
            float ls = sl[lrow + q];
            size_t ob = (size_t)(row + q) * VV + v0 + lc;
            out[ob]      = accA[q] + boA - ls;
            out[ob + 16] = accB[q] + boB - ls;
        }
    }
}

// ---------------- Launch -------------------------------------------------------
extern "C" void kernel_launch(void* const* d_in, const int* in_sizes, int n_in,
                              void* d_out, int out_size, void* d_ws, size_t ws_size,
                              hipStream_t stream) {
    const int*   y   = (const int*)  d_in[0];
    const float* enc = (const float*)d_in[1];
    const float* emb = (const float*)d_in[2];
    const float* Wi  = (const float*)d_in[3];
    const float* bi  = (const float*)d_in[4];
    const float* Wh  = (const float*)d_in[5];
    const float* bh  = (const float*)d_in[6];
    const float* Wo  = (const float*)d_in[7];
    const float* bo  = (const float*)d_in[8];
    float* out = (float*)d_out;
    float* ws  = (float*)d_ws;

    // workspace (floats) — total 319,488 floats = 1.278 MB (ws>=~7MB crashed in
    // round 3; <=1.32 MB is proven safe — hard constraint).
    float* i2h  = ws;                        // 65,536
    ushort* H0  = (ushort*)(ws + 65536);     // 3 x 65,536 ushorts = 98,304 floats
    ushort* H1  = H0 + MM * HH;
    ushort* H2  = H1 + MM * HH;
    float* pmax = ws + 163840;               // VC*MM = 51,200
    float* pamx = ws + 215040;               // 51,200
    float* psum = ws + 266240;               // 51,200
    float* lse  = ws + 317440;               // 2,048

    // W limbs: scratch inside the (not-yet-written) logprobs output region.
    ushort* W0 = (ushort*)out;               // 3 x 1,024,000 ushorts = 6.1 MB
    ushort* W1 = W0 + NWE;
    ushort* W2 = W1 + NWE;

    k_pre<<<MM + WLB, 256, 0, stream>>>(y, emb, Wi, bi, bh, Wo, i2h, W0, W1, W2);
    k_rnn<<<BB, 64, 0, stream>>>(enc, Wh, i2h, H0, H1, H2);
    dim3 gs(VC, 32);
    k_stats_mfma<<<gs, 256, 0, stream>>>(W0, W1, W2, H0, H1, H2, bo, pmax, pamx, psum);
    k_combine<<<(MM + 255) / 256, 256, 0, stream>>>(pmax, pamx, psum, lse,
                                                    out + (size_t)MM * VV);
    dim3 gw(1000, 4);
    k_write_conv<<<gw, 64, 0, stream>>>(Wo, H0, H1, H2, bo, lse, out);
}